// Round 2
// baseline (384.212 us; speedup 1.0000x reference)
//
#include <hip/hip_runtime.h>
#include <hip/hip_bf16.h>

#define Tn 512
#define Bn 512
#define Kn 128

typedef __bf16 bf16_t;
typedef __bf16 bf16x8 __attribute__((ext_vector_type(8)));
typedef float f32x4 __attribute__((ext_vector_type(4)));
typedef unsigned int u32;
typedef u32 u32x4 __attribute__((ext_vector_type(4)));

__device__ __forceinline__ u32 pack2bf(float a, float b) {
    bf16_t ha = (bf16_t)a, hb = (bf16_t)b;
    u32 ua = (u32)__builtin_bit_cast(unsigned short, ha);
    u32 ub = (u32)__builtin_bit_cast(unsigned short, hb);
    return ua | (ub << 16);
}

// ---------------- prep: E A-fragment build + numerator + out zeroing ----------------
// A-frag image: idx = (((dir*8 + m)*4 + ks)*64 + l)*8 + e
//   lane roles: c=l&15 (row slot), g=l>>4 (k-group)
//   logical k = 32*ks + 8*g + e          (shared sigma with B-frags)
//   logical row j = J(m,c) = 32*(m>>1) + 4*(m&1) + 8*(c>>2) + (c&3)
//   dir 0 (fwd):  A[j][k] = exp(trans[k][j])   (D = E^T-weighted: v@E)
//   dir 1 (bwd):  A[j][k] = exp(trans[j][k])
// J is chosen so that D's per-lane output IS the next step's B-frag layout.
__global__ void crf_prep(const float* __restrict__ em, const int* __restrict__ tags,
                         const int* __restrict__ mask, const float* __restrict__ startT,
                         const float* __restrict__ endT, const float* __restrict__ trans,
                         bf16_t* __restrict__ frags, float* __restrict__ num,
                         float* __restrict__ out)
{
    const int bid = blockIdx.x;
    const int tid = threadIdx.x;
    if (bid == Bn) {
        if (tid == 0) out[0] = 0.f;
        for (int idx = tid; idx < 2*8*4*64*8; idx += blockDim.x) {
            const int e   = idx & 7;
            const int l   = (idx >> 3) & 63;
            const int ks  = (idx >> 9) & 3;
            const int m   = (idx >> 11) & 7;
            const int dir = (idx >> 14) & 1;
            const int c = l & 15, g = l >> 4;
            const int k = 32*ks + 8*g + e;
            const int j = 32*(m >> 1) + 4*(m & 1) + 8*(c >> 2) + (c & 3);
            const float v = (dir == 0) ? trans[k*Kn + j] : trans[j*Kn + k];
            frags[idx] = (bf16_t)__expf(v);
        }
        return;
    }
    // numerator for batch b
    const int b = bid;
    float s = 0.f;
    int cnt = 0;
    for (int t = tid; t < Tn; t += blockDim.x) {
        const int mk = mask[t*Bn + b];
        cnt += (mk != 0);
        if (t >= 1 && mk != 0) {
            const int tp = tags[(t-1)*Bn + b];
            const int tc = tags[t*Bn + b];
            s += trans[tp*Kn + tc] + em[(size_t)t*Bn*Kn + (size_t)b*Kn + tc];
        }
    }
    __shared__ float sred[128];
    __shared__ int   cred[128];
    sred[tid] = s; cred[tid] = cnt;
    __syncthreads();
    for (int off = 64; off > 0; off >>= 1) {
        if (tid < off) { sred[tid] += sred[tid+off]; cred[tid] += cred[tid+off]; }
        __syncthreads();
    }
    if (tid == 0) {
        const int t0tag = tags[b];
        const float n0 = startT[t0tag] + em[(size_t)b*Kn + t0tag];
        int seq_end = cred[0] - 1;
        if (seq_end < 0) seq_end = 0;
        const int lastTag = tags[seq_end*Bn + b];
        num[b] = n0 + sred[0] + endT[lastTag];
    }
}

// ---------------- main: fully in-register linear-domain recurrence ----------------
// 64 blocks x 64 threads (1 wave = 1 chain of 16 batches, one direction).
// Per step: 32 MFMA (8 m-tiles x 4 k-slices) -> VALU exp/mul/select/pack -> next B.
// No LDS, no barriers. em prefetched ~1.5 iterations ahead in registers.

__device__ __forceinline__ void load_em(f32x4 (&dst)[8], int& mk, int midx, int dir,
                                        const float* __restrict__ em,
                                        const int* __restrict__ mask,
                                        int batch, int g)
{
    const int t_ = dir ? (511 - midx) : midx;
    const float* p = em + ((size_t)t_*Bn + batch)*Kn + 8*g;
    #pragma unroll
    for (int q = 0; q < 8; ++q) {
        const int off = 32*(q >> 1) + 4*(q & 1);
        dst[q] = *reinterpret_cast<const f32x4*>(p + off);
    }
    const int tm = dir ? (512 - midx) : midx;
    mk = mask[tm*Bn + batch];
}

__device__ __forceinline__ void step(u32 (&bq)[16], f32x4 (&up)[8], float& Cacc,
                                     const bf16x8 (&af)[8][4], const f32x4 (&emb)[8],
                                     int mkb, int midx, int dir, int c)
{
    // MFMA: acc[q] = sum_ks A[q][ks] x B[ks]
    f32x4 acc[8];
    #pragma unroll
    for (int q = 0; q < 8; ++q) acc[q] = f32x4{0.f, 0.f, 0.f, 0.f};
    #pragma unroll
    for (int ks = 0; ks < 4; ++ks) {
        u32x4 bw = { bq[4*ks], bq[4*ks+1], bq[4*ks+2], bq[4*ks+3] };
        const bf16x8 bf = __builtin_bit_cast(bf16x8, bw);
        #pragma unroll
        for (int q = 0; q < 8; ++q)
            acc[q] = __builtin_amdgcn_mfma_f32_16x16x32_bf16(af[q][ks], bf, acc[q], 0, 0, 0);
    }

    const bool mk = (mkb != 0);
    const bool rs = ((midx & 3) == 0);
    float sc = 1.f, klog = 0.f;
    if (rs) {   // exact pow-2 rescale; k from pre-step state, broadcast from g==0 lane
        int ex = (int)((bq[0] >> 7) & 0xFF) - 127;
        ex = __shfl(ex, c, 64);
        sc = __uint_as_float((u32)((127 - ex) & 0xFF) << 23);
        klog = (float)ex * 0.6931471805599453f;
    }

    if (dir == 0) {  // fwd: a_t = (a_{t-1}@E) * x_t if mask else a_{t-1}
        if (rs) {
            #pragma unroll
            for (int q = 0; q < 8; ++q)
                #pragma unroll
                for (int r = 0; r < 4; ++r) acc[q][r] *= sc;
            Cacc += mk ? klog : 0.f;
        }
        #pragma unroll
        for (int q = 0; q < 8; ++q) {
            f32x4 y;
            #pragma unroll
            for (int r = 0; r < 4; ++r) y[r] = acc[q][r] * __expf(emb[q][r]);
            const int base = 4*(q >> 1) + 2*(q & 1);
            const u32 w0 = pack2bf(y[0], y[1]);
            const u32 w1 = pack2bf(y[2], y[3]);
            bq[base]     = mk ? w0 : bq[base];
            bq[base + 1] = mk ? w1 : bq[base + 1];
        }
    } else {  // bwd: u_t = E@(x_{t+1} u_{t+1}) if mask_{t+1} else u_{t+1}; B = x_t*u_t
        #pragma unroll
        for (int q = 0; q < 8; ++q)
            #pragma unroll
            for (int r = 0; r < 4; ++r)
                up[q][r] = mk ? acc[q][r] : up[q][r];
        if (rs) {
            #pragma unroll
            for (int q = 0; q < 8; ++q)
                #pragma unroll
                for (int r = 0; r < 4; ++r) up[q][r] *= sc;
            Cacc += klog;
        }
        #pragma unroll
        for (int q = 0; q < 8; ++q) {
            f32x4 y;
            #pragma unroll
            for (int r = 0; r < 4; ++r) y[r] = up[q][r] * __expf(emb[q][r]);
            const int base = 4*(q >> 1) + 2*(q & 1);
            bq[base]     = pack2bf(y[0], y[1]);
            bq[base + 1] = pack2bf(y[2], y[3]);
        }
    }
}

__global__ __launch_bounds__(64, 1)
void crf_main(const float* __restrict__ em, const int* __restrict__ mask,
              const float* __restrict__ startT, const float* __restrict__ endT,
              const bf16_t* __restrict__ frags,
              float* __restrict__ vws, float* __restrict__ Cws)
{
    const int bid = blockIdx.x;      // 64 blocks
    const int dir = bid & 1;
    const int b0  = (bid >> 1) * 16;
    const int l = threadIdx.x;       // one wave
    const int c = l & 15, g = l >> 4;
    const int batch = b0 + c;

    // resident E fragments: 8 m-tiles x 4 k-slices
    bf16x8 af[8][4];
    {
        const bf16_t* fb = frags + (size_t)dir * 16384;
        #pragma unroll
        for (int m = 0; m < 8; ++m)
            #pragma unroll
            for (int ks = 0; ks < 4; ++ks)
                af[m][ks] = *reinterpret_cast<const bf16x8*>(fb + ((m*4 + ks)*64 + l)*8);
    }

    // init: fwd B = pack(exp(start + em_0));  bwd B = pack(exp(end + em_511)), u = exp(end)
    u32 bq[16];
    f32x4 up[8];
    float Cacc = 0.f;
    {
        const float* sv = dir ? endT : startT;
        const int t0 = dir ? 511 : 0;
        const float* p0 = em + ((size_t)t0*Bn + batch)*Kn + 8*g;
        #pragma unroll
        for (int q = 0; q < 8; ++q) {
            const int off = 32*(q >> 1) + 4*(q & 1);
            const f32x4 e4 = *reinterpret_cast<const f32x4*>(p0 + off);
            const f32x4 s4 = *reinterpret_cast<const f32x4*>(sv + 8*g + off);
            f32x4 y;
            #pragma unroll
            for (int r = 0; r < 4; ++r) {
                y[r]     = __expf(s4[r] + e4[r]);
                up[q][r] = __expf(s4[r]);
            }
            const int base = 4*(q >> 1) + 2*(q & 1);
            bq[base]     = pack2bf(y[0], y[1]);
            bq[base + 1] = pack2bf(y[2], y[3]);
        }
    }

    const int M = 256 - dir;   // fwd: 256 steps (-> a_256); bwd: 255 steps (-> u_256)
    f32x4 emA[8], emB[8];
    int mkA, mkB;
    load_em(emA, mkA, 1, dir, em, mask, batch, g);
    load_em(emB, mkB, 2, dir, em, mask, batch, g);

    int mm = 1;
    for (; mm + 1 <= M; mm += 2) {
        step(bq, up, Cacc, af, emA, mkA, mm, dir, c);
        if (mm + 2 <= M) load_em(emA, mkA, mm + 2, dir, em, mask, batch, g);
        step(bq, up, Cacc, af, emB, mkB, mm + 1, dir, c);
        if (mm + 3 <= M) load_em(emB, mkB, mm + 3, dir, em, mask, batch, g);
    }
    if (mm <= M) step(bq, up, Cacc, af, emA, mkA, mm, dir, c);

    // store final state (fwd from bf16 frags = authoritative masked state; bwd from f32 u)
    float* vrow = vws + ((size_t)(dir*Bn + batch))*Kn + 8*g;
    #pragma unroll
    for (int q = 0; q < 8; ++q) {
        const int off  = 32*(q >> 1) + 4*(q & 1);
        const int base = 4*(q >> 1) + 2*(q & 1);
        #pragma unroll
        for (int r = 0; r < 4; ++r) {
            float val;
            if (dir) {
                val = up[q][r];
            } else {
                const u32 w = (r < 2) ? bq[base] : bq[base + 1];
                const u32 h = (r & 1) ? (w >> 16) : (w & 0xffffu);
                val = __uint_as_float(h << 16);
            }
            vrow[off + r] = val;
        }
    }
    if (g == 0) Cws[dir*Bn + batch] = Cacc;
}

// ---------------- combine: den = Cf + Cb + log(a_256 . u_256); out += num - den ----------------
__global__ void crf_combine(const float* __restrict__ vws, const float* __restrict__ Cws,
                            const float* __restrict__ num, float* __restrict__ out)
{
    const int b = blockIdx.x;
    const int tid = threadIdx.x;
    const float p = vws[(size_t)b*Kn + tid] * vws[(size_t)(Bn + b)*Kn + tid];
    __shared__ float red[128];
    red[tid] = p;
    __syncthreads();
    for (int off = 64; off > 0; off >>= 1) {
        if (tid < off) red[tid] += red[tid + off];
        __syncthreads();
    }
    if (tid == 0) {
        const float den = Cws[b] + Cws[Bn + b] + logf(red[0]);
        atomicAdd(out, num[b] - den);
    }
}

extern "C" void kernel_launch(void* const* d_in, const int* in_sizes, int n_in,
                              void* d_out, int out_size, void* d_ws, size_t ws_size,
                              hipStream_t stream)
{
    const float* em     = (const float*)d_in[0];
    const int*   tags   = (const int*)d_in[1];
    const int*   mask   = (const int*)d_in[2];
    const float* startT = (const float*)d_in[3];
    const float* endT   = (const float*)d_in[4];
    const float* trans  = (const float*)d_in[5];

    char* ws = (char*)d_ws;
    bf16_t* frags = (bf16_t*)ws;                        // 65536 B
    float*  num   = (float*)(ws + 65536);               // 2048 B
    float*  Cws   = (float*)(ws + 65536 + 2048);        // 4096 B
    float*  vws   = (float*)(ws + 65536 + 2048 + 4096); // 524288 B
    float*  out   = (float*)d_out;

    hipLaunchKernelGGL(crf_prep, dim3(Bn + 1), dim3(128), 0, stream,
                       em, tags, mask, startT, endT, trans, frags, num, out);
    hipLaunchKernelGGL(crf_main, dim3(64), dim3(64), 0, stream,
                       em, mask, startT, endT, frags, vws, Cws);
    hipLaunchKernelGGL(crf_combine, dim3(Bn), dim3(128), 0, stream,
                       vws, Cws, num, out);
}

// Round 3
// 365.511 us; speedup vs baseline: 1.0512x; 1.0512x over previous
//
#include <hip/hip_runtime.h>
#include <hip/hip_bf16.h>

#define Tn 512
#define Bn 512
#define Kn 128

typedef __bf16 bf16_t;
typedef __bf16 bf16x8 __attribute__((ext_vector_type(8)));
typedef float f32x4 __attribute__((ext_vector_type(4)));
typedef unsigned int u32;
typedef u32 u32x4 __attribute__((ext_vector_type(4)));

typedef const __attribute__((address_space(1))) void* as1cv;
typedef __attribute__((address_space(3))) void* as3v;

__device__ __forceinline__ void gl_lds16(const void* g, void* s) {
    __builtin_amdgcn_global_load_lds((as1cv)g, (as3v)s, 16, 0, 0);
}
__device__ __forceinline__ void gl_lds4(const void* g, void* s) {
    __builtin_amdgcn_global_load_lds((as1cv)g, (as3v)s, 4, 0, 0);
}

__device__ __forceinline__ u32 pack2bf(float a, float b) {
    bf16_t ha = (bf16_t)a, hb = (bf16_t)b;
    u32 ua = (u32)__builtin_bit_cast(unsigned short, ha);
    u32 ub = (u32)__builtin_bit_cast(unsigned short, hb);
    return ua | (ub << 16);
}

// ---------------- prep: E A-fragment build + numerator + out zeroing ----------------
// A-frag image: idx = (((dir*8 + m)*4 + ks)*64 + l)*8 + e
//   lane roles: c=l&15, g=l>>4;  k = 32*ks + 8*g + e
//   row j = J(m,c) = 32*(m>>1) + 4*(m&1) + 8*(c>>2) + (c&3)
//   dir 0 (fwd): A[j][k] = exp(trans[k][j]);  dir 1 (bwd): A[j][k] = exp(trans[j][k])
// J chosen so D's per-lane output IS the next step's B-frag layout (verified r1/r2).
__global__ void crf_prep(const float* __restrict__ em, const int* __restrict__ tags,
                         const int* __restrict__ mask, const float* __restrict__ startT,
                         const float* __restrict__ endT, const float* __restrict__ trans,
                         bf16_t* __restrict__ frags, float* __restrict__ num,
                         float* __restrict__ out)
{
    const int bid = blockIdx.x;
    const int tid = threadIdx.x;
    if (bid == Bn) {
        if (tid == 0) out[0] = 0.f;
        for (int idx = tid; idx < 2*8*4*64*8; idx += blockDim.x) {
            const int e   = idx & 7;
            const int l   = (idx >> 3) & 63;
            const int ks  = (idx >> 9) & 3;
            const int m   = (idx >> 11) & 7;
            const int dir = (idx >> 14) & 1;
            const int c = l & 15, g = l >> 4;
            const int k = 32*ks + 8*g + e;
            const int j = 32*(m >> 1) + 4*(m & 1) + 8*(c >> 2) + (c & 3);
            const float v = (dir == 0) ? trans[k*Kn + j] : trans[j*Kn + k];
            frags[idx] = (bf16_t)__expf(v);
        }
        return;
    }
    const int b = bid;
    float s = 0.f;
    int cnt = 0;
    for (int t = tid; t < Tn; t += blockDim.x) {
        const int mk = mask[t*Bn + b];
        cnt += (mk != 0);
        if (t >= 1 && mk != 0) {
            const int tp = tags[(t-1)*Bn + b];
            const int tc = tags[t*Bn + b];
            s += trans[tp*Kn + tc] + em[(size_t)t*Bn*Kn + (size_t)b*Kn + tc];
        }
    }
    __shared__ float sred[128];
    __shared__ int   cred[128];
    sred[tid] = s; cred[tid] = cnt;
    __syncthreads();
    for (int off = 64; off > 0; off >>= 1) {
        if (tid < off) { sred[tid] += sred[tid+off]; cred[tid] += cred[tid+off]; }
        __syncthreads();
    }
    if (tid == 0) {
        const int t0tag = tags[b];
        const float n0 = startT[t0tag] + em[(size_t)b*Kn + t0tag];
        int seq_end = cred[0] - 1;
        if (seq_end < 0) seq_end = 0;
        const int lastTag = tags[seq_end*Bn + b];
        num[b] = n0 + sred[0] + endT[lastTag];
    }
}

// ---------------- main: in-register recurrence, LDS-pipelined em ----------------
// 64 blocks x 1 wave. State bf16 in VGPRs; E resident (128 VGPRs).
// em streamed via 4-deep global_load_lds pipeline, counted vmcnt(18) (never 0).
// LDS em tile: 16 rows x 32 16B-slots, slot stored at s' = rowslot ^ (row&7)
// (swizzle applied on BOTH global source and ds_read -> linear gload_lds dest).
__global__ __launch_bounds__(64, 1)
void crf_main(const float* __restrict__ em, const int* __restrict__ maskp,
              const float* __restrict__ startT, const float* __restrict__ endT,
              const bf16_t* __restrict__ frags,
              float* __restrict__ vws, float* __restrict__ Cws)
{
    const int bid = blockIdx.x;
    const int dir = bid & 1;
    const int b0  = (bid >> 1) * 16;
    const int l = threadIdx.x;
    const int c = l & 15, g = l >> 4;
    const int batch = b0 + c;

    __shared__ __align__(16) float emlds[4][2048];   // 4 x (16 rows x 128 f32)
    __shared__ int msklds[4][64];

    // resident E fragments
    bf16x8 af[8][4];
    {
        const bf16_t* fb = frags + (size_t)dir * 16384;
        #pragma unroll
        for (int m = 0; m < 8; ++m)
            #pragma unroll
            for (int ks = 0; ks < 4; ++ks)
                af[m][ks] = *reinterpret_cast<const bf16x8*>(fb + ((m*4 + ks)*64 + l)*8);
    }

    // init state
    u32 bq[16];
    f32x4 up[8];
    float Cacc = 0.f;
    {
        const float* sv = dir ? endT : startT;
        const int t0 = dir ? 511 : 0;
        const float* p0 = em + ((size_t)t0*Bn + batch)*Kn + 8*g;
        #pragma unroll
        for (int q = 0; q < 8; ++q) {
            const int off = 32*(q >> 1) + 4*(q & 1);
            const f32x4 e4 = *reinterpret_cast<const f32x4*>(p0 + off);
            const f32x4 s4 = *reinterpret_cast<const f32x4*>(sv + 8*g + off);
            f32x4 y;
            #pragma unroll
            for (int r = 0; r < 4; ++r) {
                y[r]     = __expf(s4[r] + e4[r]);
                up[q][r] = __expf(s4[r]);
            }
            const int base = 4*(q >> 1) + 2*(q & 1);
            bq[base]     = pack2bf(y[0], y[1]);
            bq[base + 1] = pack2bf(y[2], y[3]);
        }
    }

    const int M = 256 - dir;

    auto stage = [&](int midx) {
        const int t_ = dir ? (511 - midx) : midx;
        const int tm = dir ? (512 - midx) : midx;
        float* eb = &emlds[midx & 3][0];
        #pragma unroll
        for (int n = 0; n < 8; ++n) {
            const int row = 2*n + (l >> 5);
            const int sp  = l & 31;
            const int rowslot = sp ^ (row & 7);        // inverse swizzle on source
            const float* gp = em + ((size_t)t_*Bn + (size_t)(b0 + row))*Kn + rowslot*4;
            gl_lds16(gp, eb + n*256);                  // linear LDS dest
        }
        gl_lds4(maskp + (size_t)tm*Bn + b0 + (l & 15), &msklds[midx & 3][0]);
    };

    stage(1); stage(2); stage(3);

    for (int m = 1; m <= M; ++m) {
        // em[m] staged 3 steps ago; keep tiles m+1,m+2 (= 18 ops) in flight
        asm volatile("s_waitcnt vmcnt(18)" ::: "memory");

        const float* eb = &emlds[m & 3][0];
        f32x4 r[8];
        #pragma unroll
        for (int q = 0; q < 8; ++q) {
            const int slot = c*32 + ((8*(q>>1) + (q&1) + 2*g) ^ (c & 7));  // swizzled read
            r[q] = *reinterpret_cast<const f32x4*>(eb + slot*4);
        }
        const int mkv = msklds[m & 3][l];

        { int ms = m + 3; if (ms > M) ms = M; stage(ms); }  // clamp keeps vmcnt invariant

        // MFMA: acc[q] = sum_ks A[q][ks] x B[ks]
        f32x4 acc[8];
        #pragma unroll
        for (int q = 0; q < 8; ++q) acc[q] = f32x4{0.f, 0.f, 0.f, 0.f};
        #pragma unroll
        for (int ks = 0; ks < 4; ++ks) {
            u32x4 bw = { bq[4*ks], bq[4*ks+1], bq[4*ks+2], bq[4*ks+3] };
            const bf16x8 bf = __builtin_bit_cast(bf16x8, bw);
            #pragma unroll
            for (int q = 0; q < 8; ++q)
                acc[q] = __builtin_amdgcn_mfma_f32_16x16x32_bf16(af[q][ks], bf, acc[q], 0, 0, 0);
        }

        const bool mk = (mkv != 0);
        const bool rs = ((m & 3) == 0);
        float sc = 1.f, klog = 0.f;
        if (rs) {   // exact pow-2 rescale; exponent of k=0 component of batch c
            int ex = (int)((bq[0] >> 7) & 0xFF) - 127;
            ex = __shfl(ex, c, 64);
            sc = __uint_as_float((u32)((127 - ex) & 0xFF) << 23);
            klog = (float)ex * 0.6931471805599453f;
        }

        if (dir == 0) {  // fwd: v_t = (v@E)*x_t if mask else v (state & C scale paired on mk)
            #pragma unroll
            for (int q = 0; q < 8; ++q) {
                f32x4 y;
                #pragma unroll
                for (int t4 = 0; t4 < 4; ++t4) {
                    float a = acc[q][t4];
                    if (rs) a *= sc;
                    y[t4] = a * __expf(r[q][t4]);
                }
                const int base = 4*(q >> 1) + 2*(q & 1);
                const u32 w0 = pack2bf(y[0], y[1]);
                const u32 w1 = pack2bf(y[2], y[3]);
                bq[base]     = mk ? w0 : bq[base];
                bq[base + 1] = mk ? w1 : bq[base + 1];
            }
            if (rs && mk) Cacc += klog;
        } else {  // bwd: u = select(E@B, u); scale both branches; B = u*x_t
            #pragma unroll
            for (int q = 0; q < 8; ++q) {
                f32x4 y;
                #pragma unroll
                for (int t4 = 0; t4 < 4; ++t4) {
                    float un = mk ? acc[q][t4] : up[q][t4];
                    if (rs) un *= sc;
                    up[q][t4] = un;
                    y[t4] = un * __expf(r[q][t4]);
                }
                const int base = 4*(q >> 1) + 2*(q & 1);
                bq[base]     = pack2bf(y[0], y[1]);
                bq[base + 1] = pack2bf(y[2], y[3]);
            }
            if (rs) Cacc += klog;
        }
    }

    // store final state (fwd: bf16 state; bwd: f32 u)
    float* vrow = vws + ((size_t)(dir*Bn + batch))*Kn + 8*g;
    #pragma unroll
    for (int q = 0; q < 8; ++q) {
        const int off  = 32*(q >> 1) + 4*(q & 1);
        const int base = 4*(q >> 1) + 2*(q & 1);
        #pragma unroll
        for (int r = 0; r < 4; ++r) {
            float val;
            if (dir) {
                val = up[q][r];
            } else {
                const u32 w = (r < 2) ? bq[base] : bq[base + 1];
                const u32 h = (r & 1) ? (w >> 16) : (w & 0xffffu);
                val = __uint_as_float(h << 16);
            }
            vrow[off + r] = val;
        }
    }
    if (g == 0) Cws[dir*Bn + batch] = Cacc;
}

// ---------------- combine: den = Cf + Cb + log(a_256 . u_256); out += num - den ----------------
__global__ void crf_combine(const float* __restrict__ vws, const float* __restrict__ Cws,
                            const float* __restrict__ num, float* __restrict__ out)
{
    const int b = blockIdx.x;
    const int tid = threadIdx.x;
    const float p = vws[(size_t)b*Kn + tid] * vws[(size_t)(Bn + b)*Kn + tid];
    __shared__ float red[128];
    red[tid] = p;
    __syncthreads();
    for (int off = 64; off > 0; off >>= 1) {
        if (tid < off) red[tid] += red[tid + off];
        __syncthreads();
    }
    if (tid == 0) {
        const float den = Cws[b] + Cws[Bn + b] + logf(red[0]);
        atomicAdd(out, num[b] - den);
    }
}

extern "C" void kernel_launch(void* const* d_in, const int* in_sizes, int n_in,
                              void* d_out, int out_size, void* d_ws, size_t ws_size,
                              hipStream_t stream)
{
    const float* em     = (const float*)d_in[0];
    const int*   tags   = (const int*)d_in[1];
    const int*   mask   = (const int*)d_in[2];
    const float* startT = (const float*)d_in[3];
    const float* endT   = (const float*)d_in[4];
    const float* trans  = (const float*)d_in[5];

    char* ws = (char*)d_ws;
    bf16_t* frags = (bf16_t*)ws;                        // 65536 B
    float*  num   = (float*)(ws + 65536);               // 2048 B
    float*  Cws   = (float*)(ws + 65536 + 2048);        // 4096 B
    float*  vws   = (float*)(ws + 65536 + 2048 + 4096); // 524288 B
    float*  out   = (float*)d_out;

    hipLaunchKernelGGL(crf_prep, dim3(Bn + 1), dim3(128), 0, stream,
                       em, tags, mask, startT, endT, trans, frags, num, out);
    hipLaunchKernelGGL(crf_main, dim3(64), dim3(64), 0, stream,
                       em, mask, startT, endT, frags, vws, Cws);
    hipLaunchKernelGGL(crf_combine, dim3(Bn), dim3(128), 0, stream,
                       vws, Cws, num, out);
}

// Round 4
// 273.722 us; speedup vs baseline: 1.4037x; 1.3353x over previous
//
#include <hip/hip_runtime.h>
#include <hip/hip_bf16.h>

#define Tn 512
#define Bn 512
#define Kn 128

typedef __bf16 bf16_t;
typedef __bf16 bf16x8 __attribute__((ext_vector_type(8)));
typedef float f32x4 __attribute__((ext_vector_type(4)));
typedef unsigned int u32;
typedef u32 u32x4 __attribute__((ext_vector_type(4)));

__device__ __forceinline__ u32 pack2bf(float a, float b) {
    bf16_t ha = (bf16_t)a, hb = (bf16_t)b;
    u32 ua = (u32)__builtin_bit_cast(unsigned short, ha);
    u32 ub = (u32)__builtin_bit_cast(unsigned short, hb);
    return ua | (ub << 16);
}

// ---------------- prep: E A-fragment build + numerator + out zeroing ----------------
// A-frag image: idx = (((dir*8 + m)*4 + ks)*64 + l)*8 + e
//   lane roles: c=l&15, g=l>>4;  k = 32*ks + 8*g + e
//   row j = J(m,c) = 32*(m>>1) + 4*(m&1) + 8*(c>>2) + (c&3)
//   dir 0 (fwd): A[j][k] = exp(trans[k][j]);  dir 1 (bwd): A[j][k] = exp(trans[j][k])
// J chosen so D's per-lane output IS the next step's B-frag layout (verified r1-r3).
__global__ void crf_prep(const float* __restrict__ em, const int* __restrict__ tags,
                         const int* __restrict__ mask, const float* __restrict__ startT,
                         const float* __restrict__ endT, const float* __restrict__ trans,
                         bf16_t* __restrict__ frags, float* __restrict__ num,
                         float* __restrict__ out)
{
    const int bid = blockIdx.x;
    const int tid = threadIdx.x;
    if (bid == Bn) {
        if (tid == 0) out[0] = 0.f;
        for (int idx = tid; idx < 2*8*4*64*8; idx += blockDim.x) {
            const int e   = idx & 7;
            const int l   = (idx >> 3) & 63;
            const int ks  = (idx >> 9) & 3;
            const int m   = (idx >> 11) & 7;
            const int dir = (idx >> 14) & 1;
            const int c = l & 15, g = l >> 4;
            const int k = 32*ks + 8*g + e;
            const int j = 32*(m >> 1) + 4*(m & 1) + 8*(c >> 2) + (c & 3);
            const float v = (dir == 0) ? trans[k*Kn + j] : trans[j*Kn + k];
            frags[idx] = (bf16_t)__expf(v);
        }
        return;
    }
    const int b = bid;
    float s = 0.f;
    int cnt = 0;
    for (int t = tid; t < Tn; t += blockDim.x) {
        const int mk = mask[t*Bn + b];
        cnt += (mk != 0);
        if (t >= 1 && mk != 0) {
            const int tp = tags[(t-1)*Bn + b];
            const int tc = tags[t*Bn + b];
            s += trans[tp*Kn + tc] + em[(size_t)t*Bn*Kn + (size_t)b*Kn + tc];
        }
    }
    __shared__ float sred[128];
    __shared__ int   cred[128];
    sred[tid] = s; cred[tid] = cnt;
    __syncthreads();
    for (int off = 64; off > 0; off >>= 1) {
        if (tid < off) { sred[tid] += sred[tid+off]; cred[tid] += cred[tid+off]; }
        __syncthreads();
    }
    if (tid == 0) {
        const int t0tag = tags[b];
        const float n0 = startT[t0tag] + em[(size_t)b*Kn + t0tag];
        int seq_end = cred[0] - 1;
        if (seq_end < 0) seq_end = 0;
        const int lastTag = tags[seq_end*Bn + b];
        num[b] = n0 + sred[0] + endT[lastTag];
    }
}

// ---------------- main: fully in-register recurrence, reg-prefetched em ----------------
// 64 blocks x 1 wave. State bf16 in VGPRs (u32x4 per k-slice); E resident (AGPR/VGPR).
// em loaded direct-to-register 2 tiles ahead; sched_barrier(0) pins each load block at
// the iteration boundary so the compiler emits counted vmcnt (not drain-0) before use.
// No LDS, no barriers, no global_load_lds.
__global__ __launch_bounds__(64, 1)
void crf_main(const float* __restrict__ em, const int* __restrict__ maskp,
              const float* __restrict__ startT, const float* __restrict__ endT,
              const bf16_t* __restrict__ frags,
              float* __restrict__ vws, float* __restrict__ Cws)
{
    const int bid = blockIdx.x;
    const int dir = bid & 1;
    const int b0  = (bid >> 1) * 16;
    const int l = threadIdx.x;
    const int c = l & 15, g = l >> 4;
    const int batch = b0 + c;

    // resident E fragments (unified VGPR/AGPR file has room: ~280 logical < 512 budget)
    bf16x8 af[8][4];
    {
        const bf16_t* fb = frags + (size_t)dir * 16384;
        #pragma unroll
        for (int m = 0; m < 8; ++m)
            #pragma unroll
            for (int ks = 0; ks < 4; ++ks)
                af[m][ks] = *reinterpret_cast<const bf16x8*>(fb + ((m*4 + ks)*64 + l)*8);
    }

    // state: bq4[ks] = B-operand k-slice (4 u32 = 8 bf16); up = bwd f32 state
    u32x4 bq4[4];
    f32x4 up[8];
    float Cacc = 0.f;
    {
        const float* sv = dir ? endT : startT;
        const int t0 = dir ? 511 : 0;
        const float* p0 = em + ((size_t)t0*Bn + batch)*Kn + 8*g;
        #pragma unroll
        for (int q = 0; q < 8; ++q) {
            const int off = 32*(q >> 1) + 4*(q & 1);
            const f32x4 e4 = *reinterpret_cast<const f32x4*>(p0 + off);
            const f32x4 s4 = *reinterpret_cast<const f32x4*>(sv + 8*g + off);
            f32x4 y;
            #pragma unroll
            for (int r = 0; r < 4; ++r) {
                y[r]     = __expf(s4[r] + e4[r]);
                up[q][r] = __expf(s4[r]);
            }
            bq4[q >> 1][2*(q & 1)]     = pack2bf(y[0], y[1]);
            bq4[q >> 1][2*(q & 1) + 1] = pack2bf(y[2], y[3]);
        }
    }

    const int M = 256 - dir;

    auto load_tile = [&](f32x4 (&dst)[8], int& mk, int midx) {
        const int t_ = dir ? (511 - midx) : midx;
        const int tm = dir ? (512 - midx) : midx;
        const float* p = em + ((size_t)t_*Bn + batch)*Kn + 8*g;
        #pragma unroll
        for (int q = 0; q < 8; ++q) {
            const int off = 32*(q >> 1) + 4*(q & 1);
            dst[q] = *reinterpret_cast<const f32x4*>(p + off);
        }
        mk = maskp[(size_t)tm*Bn + batch];
    };

    auto iter = [&](f32x4 (&rcur)[8], int& mkcur, int m, bool rs) {
        // MFMA: acc[q] = sum_ks A[q][ks] x B[ks]   (8 independent 4-deep chains)
        f32x4 acc[8];
        #pragma unroll
        for (int q = 0; q < 8; ++q) acc[q] = f32x4{0.f, 0.f, 0.f, 0.f};
        #pragma unroll
        for (int ks = 0; ks < 4; ++ks) {
            const bf16x8 bf = __builtin_bit_cast(bf16x8, bq4[ks]);
            #pragma unroll
            for (int q = 0; q < 8; ++q)
                acc[q] = __builtin_amdgcn_mfma_f32_16x16x32_bf16(af[q][ks], bf, acc[q], 0, 0, 0);
        }

        const bool mk = (mkcur != 0);
        float sc = 1.f, klog = 0.f;
        if (rs) {   // exact pow-2 rescale; exponent of k=0 component of batch c
            int ex = (int)((bq4[0][0] >> 7) & 0xFF) - 127;
            ex = __shfl(ex, c, 64);
            sc = __uint_as_float((u32)((127 - ex) & 0xFF) << 23);
            klog = (float)ex * 0.6931471805599453f;
        }

        if (dir == 0) {  // fwd: v_t = (v@E)*x_t if mask else v (state & C scale paired on mk)
            #pragma unroll
            for (int q = 0; q < 8; ++q) {
                f32x4 y;
                #pragma unroll
                for (int t4 = 0; t4 < 4; ++t4) {
                    float a = acc[q][t4];
                    if (rs) a *= sc;
                    y[t4] = a * __expf(rcur[q][t4]);
                }
                const u32 w0 = pack2bf(y[0], y[1]);
                const u32 w1 = pack2bf(y[2], y[3]);
                const int ksw = q >> 1, e0 = 2*(q & 1);
                bq4[ksw][e0]     = mk ? w0 : bq4[ksw][e0];
                bq4[ksw][e0 + 1] = mk ? w1 : bq4[ksw][e0 + 1];
            }
            if (rs && mk) Cacc += klog;
        } else {  // bwd: u = select(E@B, u); scale both branches; B = u*x_t
            #pragma unroll
            for (int q = 0; q < 8; ++q) {
                f32x4 y;
                #pragma unroll
                for (int t4 = 0; t4 < 4; ++t4) {
                    float un = mk ? acc[q][t4] : up[q][t4];
                    if (rs) un *= sc;
                    up[q][t4] = un;
                    y[t4] = un * __expf(rcur[q][t4]);
                }
                const int ksw = q >> 1, e0 = 2*(q & 1);
                bq4[ksw][e0]     = pack2bf(y[0], y[1]);
                bq4[ksw][e0 + 1] = pack2bf(y[2], y[3]);
            }
            if (rs) Cacc += klog;
        }

        // prefetch tile m+2 into the just-consumed buffer; clamp keeps loads in-bounds.
        int ms = m + 2; if (ms > M) ms = M;
        load_tile(rcur, mkcur, ms);
        __builtin_amdgcn_sched_barrier(0);   // pin loads at iteration boundary (no sinking)
    };

    f32x4 emA[8], emB[8];
    int mkA, mkB;
    load_tile(emA, mkA, 1);
    load_tile(emB, mkB, 2);
    __builtin_amdgcn_sched_barrier(0);

    int m = 1;
    for (; m + 3 <= M; m += 4) {       // rs static: only (m+3)%4==0 rescales
        iter(emA, mkA, m,     false);
        iter(emB, mkB, m + 1, false);
        iter(emA, mkA, m + 2, false);
        iter(emB, mkB, m + 3, true);
    }
    for (; m <= M; ++m) {              // bwd tail m=253..255 (never a rescale step)
        if (m & 1) iter(emA, mkA, m, false);
        else       iter(emB, mkB, m, false);
    }

    // store final state (fwd: bf16 state; bwd: f32 u)
    float* vrow = vws + ((size_t)(dir*Bn + batch))*Kn + 8*g;
    #pragma unroll
    for (int q = 0; q < 8; ++q) {
        const int off = 32*(q >> 1) + 4*(q & 1);
        const int ksw = q >> 1, e0 = 2*(q & 1);
        #pragma unroll
        for (int r = 0; r < 4; ++r) {
            float val;
            if (dir) {
                val = up[q][r];
            } else {
                const u32 w = (r < 2) ? bq4[ksw][e0] : bq4[ksw][e0 + 1];
                const u32 h = (r & 1) ? (w >> 16) : (w & 0xffffu);
                val = __uint_as_float(h << 16);
            }
            vrow[off + r] = val;
        }
    }
    if (g == 0) Cws[dir*Bn + batch] = Cacc;
}

// ---------------- combine: den = Cf + Cb + log(a_256 . u_256); out += num - den ----------------
__global__ void crf_combine(const float* __restrict__ vws, const float* __restrict__ Cws,
                            const float* __restrict__ num, float* __restrict__ out)
{
    const int b = blockIdx.x;
    const int tid = threadIdx.x;
    const float p = vws[(size_t)b*Kn + tid] * vws[(size_t)(Bn + b)*Kn + tid];
    __shared__ float red[128];
    red[tid] = p;
    __syncthreads();
    for (int off = 64; off > 0; off >>= 1) {
        if (tid < off) red[tid] += red[tid + off];
        __syncthreads();
    }
    if (tid == 0) {
        const float den = Cws[b] + Cws[Bn + b] + logf(red[0]);
        atomicAdd(out, num[b] - den);
    }
}

extern "C" void kernel_launch(void* const* d_in, const int* in_sizes, int n_in,
                              void* d_out, int out_size, void* d_ws, size_t ws_size,
                              hipStream_t stream)
{
    const float* em     = (const float*)d_in[0];
    const int*   tags   = (const int*)d_in[1];
    const int*   mask   = (const int*)d_in[2];
    const float* startT = (const float*)d_in[3];
    const float* endT   = (const float*)d_in[4];
    const float* trans  = (const float*)d_in[5];

    char* ws = (char*)d_ws;
    bf16_t* frags = (bf16_t*)ws;                        // 65536 B
    float*  num   = (float*)(ws + 65536);               // 2048 B
    float*  Cws   = (float*)(ws + 65536 + 2048);        // 4096 B
    float*  vws   = (float*)(ws + 65536 + 2048 + 4096); // 524288 B
    float*  out   = (float*)d_out;

    hipLaunchKernelGGL(crf_prep, dim3(Bn + 1), dim3(128), 0, stream,
                       em, tags, mask, startT, endT, trans, frags, num, out);
    hipLaunchKernelGGL(crf_main, dim3(64), dim3(64), 0, stream,
                       em, mask, startT, endT, frags, vws, Cws);
    hipLaunchKernelGGL(crf_combine, dim3(Bn), dim3(128), 0, stream,
                       vws, Cws, num, out);
}

// Round 5
// 255.241 us; speedup vs baseline: 1.5053x; 1.0724x over previous
//
#include <hip/hip_runtime.h>
#include <hip/hip_bf16.h>

#define Tn 512
#define Bn 512
#define Kn 128

typedef __bf16 bf16_t;
typedef __bf16 bf16x8 __attribute__((ext_vector_type(8)));
typedef float f32x4 __attribute__((ext_vector_type(4)));
typedef unsigned int u32;
typedef u32 u32x4 __attribute__((ext_vector_type(4)));

__device__ __forceinline__ u32 pack2bf(float a, float b) {
    bf16_t ha = (bf16_t)a, hb = (bf16_t)b;
    u32 ua = (u32)__builtin_bit_cast(unsigned short, ha);
    u32 ub = (u32)__builtin_bit_cast(unsigned short, hb);
    return ua | (ub << 16);
}

// ---------------- expem: X[t,b,k] = bf16(exp(em[t,b,k])) ----------------
// Pure elementwise hoist of the recurrence's per-step exp. Memory-bound:
// 67MB read + 33.5MB write.
__global__ __launch_bounds__(256)
void crf_expem(const float* __restrict__ em, u32* __restrict__ X)
{
    const size_t N = (size_t)Tn * Bn * Kn;
    const size_t nth = (size_t)gridDim.x * blockDim.x;
    for (size_t base = ((size_t)blockIdx.x * blockDim.x + threadIdx.x) * 8; base < N;
         base += nth * 8) {
        const f32x4 a = *reinterpret_cast<const f32x4*>(em + base);
        const f32x4 b = *reinterpret_cast<const f32x4*>(em + base + 4);
        u32x4 w;
        w[0] = pack2bf(__expf(a[0]), __expf(a[1]));
        w[1] = pack2bf(__expf(a[2]), __expf(a[3]));
        w[2] = pack2bf(__expf(b[0]), __expf(b[1]));
        w[3] = pack2bf(__expf(b[2]), __expf(b[3]));
        *reinterpret_cast<u32x4*>(X + base / 2) = w;
    }
}

// ---------------- prep: E A-fragment build + numerator + out zeroing ----------------
// A-frag image: idx = (((dir*8 + m)*4 + ks)*64 + l)*8 + e
//   lane roles: c=l&15, g=l>>4;  k = 32*ks + 8*g + e
//   row j = J(m,c) = 32*(m>>1) + 4*(m&1) + 8*(c>>2) + (c&3)
//   dir 0 (fwd): A[j][k] = exp(trans[k][j]);  dir 1 (bwd): A[j][k] = exp(trans[j][k])
// J chosen so D's per-lane output IS the next step's B-frag layout (verified r1-r4).
__global__ void crf_prep(const float* __restrict__ em, const int* __restrict__ tags,
                         const int* __restrict__ mask, const float* __restrict__ startT,
                         const float* __restrict__ endT, const float* __restrict__ trans,
                         bf16_t* __restrict__ frags, float* __restrict__ num,
                         float* __restrict__ out)
{
    const int bid = blockIdx.x;
    const int tid = threadIdx.x;
    if (bid == Bn) {
        if (tid == 0) out[0] = 0.f;
        for (int idx = tid; idx < 2*8*4*64*8; idx += blockDim.x) {
            const int e   = idx & 7;
            const int l   = (idx >> 3) & 63;
            const int ks  = (idx >> 9) & 3;
            const int m   = (idx >> 11) & 7;
            const int dir = (idx >> 14) & 1;
            const int c = l & 15, g = l >> 4;
            const int k = 32*ks + 8*g + e;
            const int j = 32*(m >> 1) + 4*(m & 1) + 8*(c >> 2) + (c & 3);
            const float v = (dir == 0) ? trans[k*Kn + j] : trans[j*Kn + k];
            frags[idx] = (bf16_t)__expf(v);
        }
        return;
    }
    const int b = bid;
    float s = 0.f;
    int cnt = 0;
    for (int t = tid; t < Tn; t += blockDim.x) {
        const int mk = mask[t*Bn + b];
        cnt += (mk != 0);
        if (t >= 1 && mk != 0) {
            const int tp = tags[(t-1)*Bn + b];
            const int tc = tags[t*Bn + b];
            s += trans[tp*Kn + tc] + em[(size_t)t*Bn*Kn + (size_t)b*Kn + tc];
        }
    }
    __shared__ float sred[128];
    __shared__ int   cred[128];
    sred[tid] = s; cred[tid] = cnt;
    __syncthreads();
    for (int off = 64; off > 0; off >>= 1) {
        if (tid < off) { sred[tid] += sred[tid+off]; cred[tid] += cred[tid+off]; }
        __syncthreads();
    }
    if (tid == 0) {
        const int t0tag = tags[b];
        const float n0 = startT[t0tag] + em[(size_t)b*Kn + t0tag];
        int seq_end = cred[0] - 1;
        if (seq_end < 0) seq_end = 0;
        const int lastTag = tags[seq_end*Bn + b];
        num[b] = n0 + sred[0] + endT[lastTag];
    }
}

// ---------------- main: fully in-register recurrence ----------------
// 64 blocks x 1 wave. State bf16 in VGPRs; E resident in AGPR/VGPR.
// PRE=1: em pre-exponentiated to bf16 X (4 dwordx4/step, no in-loop exp).
// PRE=0: fallback, f32 em + in-loop __expf (r4 behavior).
// Loads pinned 2 tiles ahead by sched_barrier(0) at iteration boundary.
template<int PRE>
__global__ __launch_bounds__(64, 1)
void crf_main(const float* __restrict__ em, const u32* __restrict__ Xp,
              const int* __restrict__ maskp,
              const float* __restrict__ startT, const float* __restrict__ endT,
              const bf16_t* __restrict__ frags,
              float* __restrict__ vws, float* __restrict__ Cws)
{
    const int bid = blockIdx.x;
    const int dir = bid & 1;
    const int b0  = (bid >> 1) * 16;
    const int l = threadIdx.x;
    const int c = l & 15, g = l >> 4;
    const int batch = b0 + c;

    // resident E fragments
    bf16x8 af[8][4];
    {
        const bf16_t* fb = frags + (size_t)dir * 16384;
        #pragma unroll
        for (int m = 0; m < 8; ++m)
            #pragma unroll
            for (int ks = 0; ks < 4; ++ks)
                af[m][ks] = *reinterpret_cast<const bf16x8*>(fb + ((m*4 + ks)*64 + l)*8);
    }

    // state: bq4[ks] = B-operand k-slice (4 u32 = 8 bf16); up = bwd f32 state
    u32x4 bq4[4];
    f32x4 up[8];
    float Cacc = 0.f;
    {
        const float* sv = dir ? endT : startT;
        const int t0 = dir ? 511 : 0;
        const float* p0 = em + ((size_t)t0*Bn + batch)*Kn + 8*g;
        #pragma unroll
        for (int q = 0; q < 8; ++q) {
            const int off = 32*(q >> 1) + 4*(q & 1);
            const f32x4 e4 = *reinterpret_cast<const f32x4*>(p0 + off);
            const f32x4 s4 = *reinterpret_cast<const f32x4*>(sv + 8*g + off);
            f32x4 y;
            #pragma unroll
            for (int r = 0; r < 4; ++r) {
                y[r]     = __expf(s4[r] + e4[r]);
                up[q][r] = __expf(s4[r]);
            }
            bq4[q >> 1][2*(q & 1)]     = pack2bf(y[0], y[1]);
            bq4[q >> 1][2*(q & 1) + 1] = pack2bf(y[2], y[3]);
        }
    }

    const int M = 256 - dir;

    // PRE=1 tile: 4 u32x4 (32 bf16); PRE=0 tile: 8 f32x4
    u32x4 xA[4], xB[4];
    f32x4 eA[8], eB[8];
    int mkA, mkB;

    auto load_tile = [&](u32x4 (&xd)[4], f32x4 (&ed)[8], int& mk, int midx) {
        const int t_ = dir ? (511 - midx) : midx;
        const int tm = dir ? (512 - midx) : midx;
        if (PRE) {
            const u32* wp = Xp + (((size_t)t_*Bn + batch)*Kn >> 1) + 4*g;
            #pragma unroll
            for (int s = 0; s < 4; ++s)
                xd[s] = *reinterpret_cast<const u32x4*>(wp + 16*s);
        } else {
            const float* p = em + ((size_t)t_*Bn + batch)*Kn + 8*g;
            #pragma unroll
            for (int q = 0; q < 8; ++q) {
                const int off = 32*(q >> 1) + 4*(q & 1);
                ed[q] = *reinterpret_cast<const f32x4*>(p + off);
            }
        }
        mk = maskp[(size_t)tm*Bn + batch];
    };

    auto iter = [&](u32x4 (&xcur)[4], f32x4 (&ecur)[8], int& mkcur, int m, bool rs) {
        // MFMA: acc[q] = sum_ks A[q][ks] x B[ks]
        f32x4 acc[8];
        #pragma unroll
        for (int q = 0; q < 8; ++q) acc[q] = f32x4{0.f, 0.f, 0.f, 0.f};
        #pragma unroll
        for (int ks = 0; ks < 4; ++ks) {
            const bf16x8 bf = __builtin_bit_cast(bf16x8, bq4[ks]);
            #pragma unroll
            for (int q = 0; q < 8; ++q)
                acc[q] = __builtin_amdgcn_mfma_f32_16x16x32_bf16(af[q][ks], bf, acc[q], 0, 0, 0);
        }

        const bool mk = (mkcur != 0);
        float sc = 1.f, klog = 0.f;
        if (rs) {   // exact pow-2 rescale; exponent of k=0 component of batch c
            int ex = (int)((bq4[0][0] >> 7) & 0xFF) - 127;
            ex = __shfl(ex, c, 64);
            sc = __uint_as_float((u32)((127 - ex) & 0xFF) << 23);
            klog = (float)ex * 0.6931471805599453f;
        }

        // x factor for (q,t4): PRE: unpack bf16; else exp(em)
        auto xfac = [&](int q, int t4) -> float {
            if (PRE) {
                const u32 w = xcur[q >> 1][2*(q & 1) + (t4 >> 1)];
                return __uint_as_float((t4 & 1) ? (w & 0xffff0000u) : (w << 16));
            }
            return __expf(ecur[q][t4]);
        };

        if (dir == 0) {  // fwd: v_t = (v@E)*x_t if mask else v
            #pragma unroll
            for (int q = 0; q < 8; ++q) {
                f32x4 y;
                #pragma unroll
                for (int t4 = 0; t4 < 4; ++t4) {
                    float a = acc[q][t4];
                    if (rs) a *= sc;
                    y[t4] = a * xfac(q, t4);
                }
                const u32 w0 = pack2bf(y[0], y[1]);
                const u32 w1 = pack2bf(y[2], y[3]);
                const int ksw = q >> 1, e0 = 2*(q & 1);
                bq4[ksw][e0]     = mk ? w0 : bq4[ksw][e0];
                bq4[ksw][e0 + 1] = mk ? w1 : bq4[ksw][e0 + 1];
            }
            if (rs && mk) Cacc += klog;
        } else {  // bwd: u = select(E@B, u); scale both branches; B = u*x_t
            #pragma unroll
            for (int q = 0; q < 8; ++q) {
                f32x4 y;
                #pragma unroll
                for (int t4 = 0; t4 < 4; ++t4) {
                    float un = mk ? acc[q][t4] : up[q][t4];
                    if (rs) un *= sc;
                    up[q][t4] = un;
                    y[t4] = un * xfac(q, t4);
                }
                const int ksw = q >> 1, e0 = 2*(q & 1);
                bq4[ksw][e0]     = pack2bf(y[0], y[1]);
                bq4[ksw][e0 + 1] = pack2bf(y[2], y[3]);
            }
            if (rs) Cacc += klog;
        }

        // prefetch tile m+2 into just-consumed buffer; clamp keeps vmcnt invariant
        int ms = m + 2; if (ms > M) ms = M;
        load_tile(xcur, ecur, mkcur, ms);
        __builtin_amdgcn_sched_barrier(0);   // pin loads at iteration boundary
    };

    load_tile(xA, eA, mkA, 1);
    load_tile(xB, eB, mkB, 2);
    __builtin_amdgcn_sched_barrier(0);

    int m = 1;
    for (; m + 3 <= M; m += 4) {       // rs static: only (m+3)%4==0 rescales
        iter(xA, eA, mkA, m,     false);
        iter(xB, eB, mkB, m + 1, false);
        iter(xA, eA, mkA, m + 2, false);
        iter(xB, eB, mkB, m + 3, true);
    }
    for (; m <= M; ++m) {              // bwd tail m=253..255 (never a rescale step)
        if (m & 1) iter(xA, eA, mkA, m, false);
        else       iter(xB, eB, mkB, m, false);
    }

    // store final state (fwd: bf16 state; bwd: f32 u)
    float* vrow = vws + ((size_t)(dir*Bn + batch))*Kn + 8*g;
    #pragma unroll
    for (int q = 0; q < 8; ++q) {
        const int off = 32*(q >> 1) + 4*(q & 1);
        const int ksw = q >> 1, e0 = 2*(q & 1);
        #pragma unroll
        for (int r = 0; r < 4; ++r) {
            float val;
            if (dir) {
                val = up[q][r];
            } else {
                const u32 w = (r < 2) ? bq4[ksw][e0] : bq4[ksw][e0 + 1];
                const u32 h = (r & 1) ? (w >> 16) : (w & 0xffffu);
                val = __uint_as_float(h << 16);
            }
            vrow[off + r] = val;
        }
    }
    if (g == 0) Cws[dir*Bn + batch] = Cacc;
}

// ---------------- combine: den = Cf + Cb + log(a_256 . u_256); out += num - den ----------------
__global__ void crf_combine(const float* __restrict__ vws, const float* __restrict__ Cws,
                            const float* __restrict__ num, float* __restrict__ out)
{
    const int b = blockIdx.x;
    const int tid = threadIdx.x;
    const float p = vws[(size_t)b*Kn + tid] * vws[(size_t)(Bn + b)*Kn + tid];
    __shared__ float red[128];
    red[tid] = p;
    __syncthreads();
    for (int off = 64; off > 0; off >>= 1) {
        if (tid < off) red[tid] += red[tid + off];
        __syncthreads();
    }
    if (tid == 0) {
        const float den = Cws[b] + Cws[Bn + b] + logf(red[0]);
        atomicAdd(out, num[b] - den);
    }
}

extern "C" void kernel_launch(void* const* d_in, const int* in_sizes, int n_in,
                              void* d_out, int out_size, void* d_ws, size_t ws_size,
                              hipStream_t stream)
{
    const float* em     = (const float*)d_in[0];
    const int*   tags   = (const int*)d_in[1];
    const int*   mask   = (const int*)d_in[2];
    const float* startT = (const float*)d_in[3];
    const float* endT   = (const float*)d_in[4];
    const float* trans  = (const float*)d_in[5];

    const size_t XBYTES = (size_t)Tn * Bn * Kn * 2;         // 33.5 MB
    const size_t SMALL  = 65536 + 2048 + 4096 + 524288;     // frags+num+Cws+vws
    const bool pre = (ws_size >= XBYTES + SMALL);

    char* ws = (char*)d_ws;
    u32*  X  = (u32*)ws;                                    // PRE path only
    char* base = pre ? (ws + XBYTES) : ws;
    bf16_t* frags = (bf16_t*)base;
    float*  num   = (float*)(base + 65536);
    float*  Cws   = (float*)(base + 65536 + 2048);
    float*  vws   = (float*)(base + 65536 + 2048 + 4096);
    float*  out   = (float*)d_out;

    hipLaunchKernelGGL(crf_prep, dim3(Bn + 1), dim3(128), 0, stream,
                       em, tags, mask, startT, endT, trans, frags, num, out);
    if (pre) {
        hipLaunchKernelGGL(crf_expem, dim3(4096), dim3(256), 0, stream, em, X);
        hipLaunchKernelGGL((crf_main<1>), dim3(64), dim3(64), 0, stream,
                           em, X, mask, startT, endT, frags, vws, Cws);
    } else {
        hipLaunchKernelGGL((crf_main<0>), dim3(64), dim3(64), 0, stream,
                           em, X, mask, startT, endT, frags, vws, Cws);
    }
    hipLaunchKernelGGL(crf_combine, dim3(Bn), dim3(128), 0, stream,
                       vws, Cws, num, out);
}

// Round 6
// 196.519 us; speedup vs baseline: 1.9551x; 1.2988x over previous
//
#include <hip/hip_runtime.h>
#include <hip/hip_bf16.h>

#define Tn 512
#define Bn 512
#define Kn 128

typedef __bf16 bf16_t;
typedef __bf16 bf16x8 __attribute__((ext_vector_type(8)));
typedef float f32x4 __attribute__((ext_vector_type(4)));
typedef unsigned int u32;
typedef u32 u32x4 __attribute__((ext_vector_type(4)));

__device__ __forceinline__ u32 pack2bf(float a, float b) {
    bf16_t ha = (bf16_t)a, hb = (bf16_t)b;
    u32 ua = (u32)__builtin_bit_cast(unsigned short, ha);
    u32 ub = (u32)__builtin_bit_cast(unsigned short, hb);
    return ua | (ub << 16);
}

// ---------------- expem: X[t,b,k] = bf16(exp(em[t,b,k])) ----------------
__global__ __launch_bounds__(256)
void crf_expem(const float* __restrict__ em, u32* __restrict__ X)
{
    const size_t N = (size_t)Tn * Bn * Kn;
    const size_t nth = (size_t)gridDim.x * blockDim.x;
    for (size_t base = ((size_t)blockIdx.x * blockDim.x + threadIdx.x) * 8; base < N;
         base += nth * 8) {
        const f32x4 a = *reinterpret_cast<const f32x4*>(em + base);
        const f32x4 b = *reinterpret_cast<const f32x4*>(em + base + 4);
        u32x4 w;
        w[0] = pack2bf(__expf(a[0]), __expf(a[1]));
        w[1] = pack2bf(__expf(a[2]), __expf(a[3]));
        w[2] = pack2bf(__expf(b[0]), __expf(b[1]));
        w[3] = pack2bf(__expf(b[2]), __expf(b[3]));
        *reinterpret_cast<u32x4*>(X + base / 2) = w;
    }
}

// ---------------- prep: E A-fragment build + numerator + out zeroing ----------------
// A-frag image: idx = (((dir*8 + m)*4 + ks)*64 + l)*8 + e
//   lane roles: c=l&15, g=l>>4;  k = 32*ks + 8*g + e
//   row j = J(m,c) = 32*(m>>1) + 4*(m&1) + 8*(c>>2) + (c&3)
//   dir 0 (fwd): A[j][k] = exp(trans[k][j]);  dir 1 (bwd): A[j][k] = exp(trans[j][k])
// J chosen so D's per-lane output IS the next step's B-frag layout (verified r1-r5).
__global__ void crf_prep(const float* __restrict__ em, const int* __restrict__ tags,
                         const int* __restrict__ mask, const float* __restrict__ startT,
                         const float* __restrict__ endT, const float* __restrict__ trans,
                         bf16_t* __restrict__ frags, float* __restrict__ num,
                         float* __restrict__ out)
{
    const int bid = blockIdx.x;
    const int tid = threadIdx.x;
    if (bid == Bn) {
        if (tid == 0) out[0] = 0.f;
        for (int idx = tid; idx < 2*8*4*64*8; idx += blockDim.x) {
            const int e   = idx & 7;
            const int l   = (idx >> 3) & 63;
            const int ks  = (idx >> 9) & 3;
            const int m   = (idx >> 11) & 7;
            const int dir = (idx >> 14) & 1;
            const int c = l & 15, g = l >> 4;
            const int k = 32*ks + 8*g + e;
            const int j = 32*(m >> 1) + 4*(m & 1) + 8*(c >> 2) + (c & 3);
            const float v = (dir == 0) ? trans[k*Kn + j] : trans[j*Kn + k];
            frags[idx] = (bf16_t)__expf(v);
        }
        return;
    }
    const int b = bid;
    float s = 0.f;
    int cnt = 0;
    for (int t = tid; t < Tn; t += blockDim.x) {
        const int mk = mask[t*Bn + b];
        cnt += (mk != 0);
        if (t >= 1 && mk != 0) {
            const int tp = tags[(t-1)*Bn + b];
            const int tc = tags[t*Bn + b];
            s += trans[tp*Kn + tc] + em[(size_t)t*Bn*Kn + (size_t)b*Kn + tc];
        }
    }
    __shared__ float sred[128];
    __shared__ int   cred[128];
    sred[tid] = s; cred[tid] = cnt;
    __syncthreads();
    for (int off = 64; off > 0; off >>= 1) {
        if (tid < off) { sred[tid] += sred[tid+off]; cred[tid] += cred[tid+off]; }
        __syncthreads();
    }
    if (tid == 0) {
        const int t0tag = tags[b];
        const float n0 = startT[t0tag] + em[(size_t)b*Kn + t0tag];
        int seq_end = cred[0] - 1;
        if (seq_end < 0) seq_end = 0;
        const int lastTag = tags[seq_end*Bn + b];
        num[b] = n0 + sred[0] + endT[lastTag];
    }
}

// ---------------- main: 4-wave j-split recurrence, LDS state exchange ----------------
// 64 blocks x 256 threads (4 waves on 4 SIMDs of one CU). Wave w owns m-tiles
// {2w,2w+1} -> produces state k-slice ks=w. Full state exchanged via 8KB
// double-buffered LDS, one raw s_barrier per step (manual lgkmcnt, vmcnt untouched
// so the X prefetch stays in flight). All register indexing compile-time.
template<int PRE>
__global__ __launch_bounds__(256, 1)
void crf_main(const float* __restrict__ em, const u32* __restrict__ Xp,
              const int* __restrict__ maskp,
              const float* __restrict__ startT, const float* __restrict__ endT,
              const bf16_t* __restrict__ frags,
              float* __restrict__ vws, float* __restrict__ Cws)
{
    const int bid = blockIdx.x;
    const int dir = bid & 1;
    const int b0  = (bid >> 1) * 16;
    const int tid = threadIdx.x;
    const int w   = tid >> 6;          // wave id: owns m-tiles {2w,2w+1}, slice ks=w
    const int l   = tid & 63;
    const int c = l & 15, g = l >> 4;
    const int batch = b0 + c;

    __shared__ __align__(16) u32x4 exchg[2][4][64];   // [parity][slice][lane]

    // resident E fragments for own m-tiles
    bf16x8 af[2][4];
    {
        const bf16_t* fb = frags + (size_t)dir * 16384;
        #pragma unroll
        for (int i = 0; i < 2; ++i)
            #pragma unroll
            for (int ks = 0; ks < 4; ++ks)
                af[i][ks] = *reinterpret_cast<const bf16x8*>(fb + (((2*w + i)*4 + ks)*64 + l)*8);
    }

    // init own state slice (+ bwd f32 state)
    f32x4 up[2];
    float Cacc = 0.f;
    {
        const float* sv = dir ? endT : startT;
        const int t0 = dir ? 511 : 0;
        const float* p0 = em + ((size_t)t0*Bn + batch)*Kn + 8*g;
        u32x4 own;
        #pragma unroll
        for (int i = 0; i < 2; ++i) {
            const int off = 32*w + 4*i;
            const f32x4 e4 = *reinterpret_cast<const f32x4*>(p0 + off);
            const f32x4 s4 = *reinterpret_cast<const f32x4*>(sv + 8*g + off);
            f32x4 y;
            #pragma unroll
            for (int r = 0; r < 4; ++r) {
                y[r]      = __expf(s4[r] + e4[r]);
                up[i][r]  = __expf(s4[r]);
            }
            own[2*i]     = pack2bf(y[0], y[1]);
            own[2*i + 1] = pack2bf(y[2], y[3]);
        }
        exchg[1][w][l] = own;   // iter m=1 reads parity 1
    }

    const int M = 256 - dir;

    // x tile per wave: own 8 bf16 (1 dwordx4) or 8 f32 (PRE=0)
    u32x4 xA, xB;
    f32x4 eA[2], eB[2];
    int mkA, mkB;

    auto load_tile = [&](u32x4& xd, f32x4 (&ed)[2], int& mk, int midx) {
        const int t_ = dir ? (511 - midx) : midx;
        const int tm = dir ? (512 - midx) : midx;
        if (PRE) {
            const u32* wp = Xp + (((size_t)t_*Bn + batch)*Kn >> 1) + 4*g + 16*w;
            xd = *reinterpret_cast<const u32x4*>(wp);
        } else {
            const float* p = em + ((size_t)t_*Bn + batch)*Kn + 8*g + 32*w;
            ed[0] = *reinterpret_cast<const f32x4*>(p);
            ed[1] = *reinterpret_cast<const f32x4*>(p + 4);
        }
        mk = maskp[(size_t)tm*Bn + batch];
    };

    auto iter = [&](u32x4& xcur, f32x4 (&ecur)[2], int& mkcur, int m, bool rs, int par) {
        // release own write of previous step, sync, then read full state
        asm volatile("s_waitcnt lgkmcnt(0)" ::: "memory");
        __builtin_amdgcn_s_barrier();
        __builtin_amdgcn_sched_barrier(0);

        u32x4 bs[4];
        bs[0] = exchg[par][0][l];
        bs[1] = exchg[par][1][l];
        bs[2] = exchg[par][2][l];
        bs[3] = exchg[par][3][l];
        const u32x4 ownold = exchg[par][w][l];   // fwd mask-keep source

        f32x4 acc[2];
        acc[0] = f32x4{0.f, 0.f, 0.f, 0.f};
        acc[1] = f32x4{0.f, 0.f, 0.f, 0.f};
        #pragma unroll
        for (int ks = 0; ks < 4; ++ks) {
            const bf16x8 bf = __builtin_bit_cast(bf16x8, bs[ks]);
            acc[0] = __builtin_amdgcn_mfma_f32_16x16x32_bf16(af[0][ks], bf, acc[0], 0, 0, 0);
            acc[1] = __builtin_amdgcn_mfma_f32_16x16x32_bf16(af[1][ks], bf, acc[1], 0, 0, 0);
        }

        const bool mk = (mkcur != 0);
        float sc = 1.f, klog = 0.f;
        if (rs) {   // exact pow-2 rescale; exponent of k=0 component of batch c
            int ex = (int)((bs[0][0] >> 7) & 0xFF) - 127;
            ex = __shfl(ex, c, 64);
            sc = __uint_as_float((u32)((127 - ex) & 0xFF) << 23);
            klog = (float)ex * 0.6931471805599453f;
        }

        auto xfac = [&](int i, int t4) -> float {
            if (PRE) {
                const u32 wv = xcur[2*i + (t4 >> 1)];
                return __uint_as_float((t4 & 1) ? (wv & 0xffff0000u) : (wv << 16));
            }
            return __expf(ecur[i][t4]);
        };

        u32x4 nw;
        if (dir == 0) {  // fwd: v_t = (v@E)*x_t if mask else v
            #pragma unroll
            for (int i = 0; i < 2; ++i) {
                f32x4 y;
                #pragma unroll
                for (int t4 = 0; t4 < 4; ++t4) {
                    float a = acc[i][t4];
                    if (rs) a *= sc;
                    y[t4] = a * xfac(i, t4);
                }
                nw[2*i]     = pack2bf(y[0], y[1]);
                nw[2*i + 1] = pack2bf(y[2], y[3]);
            }
            #pragma unroll
            for (int j = 0; j < 4; ++j) nw[j] = mk ? nw[j] : ownold[j];
            if (rs && mk) Cacc += klog;
        } else {  // bwd: u = select(E@B, u); scale both branches; B = u*x_t
            #pragma unroll
            for (int i = 0; i < 2; ++i) {
                f32x4 y;
                #pragma unroll
                for (int t4 = 0; t4 < 4; ++t4) {
                    float un = mk ? acc[i][t4] : up[i][t4];
                    if (rs) un *= sc;
                    up[i][t4] = un;
                    y[t4] = un * xfac(i, t4);
                }
                nw[2*i]     = pack2bf(y[0], y[1]);
                nw[2*i + 1] = pack2bf(y[2], y[3]);
            }
            if (rs) Cacc += klog;
        }

        exchg[par ^ 1][w][l] = nw;          // next step's state slice

        int ms = m + 2; if (ms > M) ms = M; // clamp keeps vmem count invariant
        load_tile(xcur, ecur, mkcur, ms);
        __builtin_amdgcn_sched_barrier(0xF); // ALU/VALU/SALU/MFMA may cross; VMEM+DS pinned
    };

    load_tile(xA, eA, mkA, 1);
    load_tile(xB, eB, mkB, 2);
    __builtin_amdgcn_sched_barrier(0xF);

    int m = 1;
    for (; m + 3 <= M; m += 4) {       // rs static: only (m+3)%4==0 rescales; par static
        iter(xA, eA, mkA, m,     false, 1);
        iter(xB, eB, mkB, m + 1, false, 0);
        iter(xA, eA, mkA, m + 2, false, 1);
        iter(xB, eB, mkB, m + 3, true,  0);
    }
    for (; m <= M; ++m) {              // bwd tail m=253..255 (never a rescale step)
        if (m & 1) iter(xA, eA, mkA, m, false, m & 1);
        else       iter(xB, eB, mkB, m, false, m & 1);
    }

    // final own state: fwd from LDS (last written slice), bwd from f32 up
    asm volatile("s_waitcnt lgkmcnt(0)" ::: "memory");
    const u32x4 fin = exchg[(M + 1) & 1][w][l];
    float* vrow = vws + ((size_t)(dir*Bn + batch))*Kn + 8*g;
    #pragma unroll
    for (int i = 0; i < 2; ++i) {
        const int off = 32*w + 4*i;
        #pragma unroll
        for (int r = 0; r < 4; ++r) {
            float val;
            if (dir) {
                val = up[i][r];
            } else {
                const u32 wv = fin[2*i + (r >> 1)];
                const u32 h  = (r & 1) ? (wv >> 16) : (wv & 0xffffu);
                val = __uint_as_float(h << 16);
            }
            vrow[off + r] = val;
        }
    }
    if (w == 0 && g == 0) Cws[dir*Bn + batch] = Cacc;
}

// ---------------- combine: den = Cf + Cb + log(a_256 . u_256); out += num - den ----------------
__global__ void crf_combine(const float* __restrict__ vws, const float* __restrict__ Cws,
                            const float* __restrict__ num, float* __restrict__ out)
{
    const int b = blockIdx.x;
    const int tid = threadIdx.x;
    const float p = vws[(size_t)b*Kn + tid] * vws[(size_t)(Bn + b)*Kn + tid];
    __shared__ float red[128];
    red[tid] = p;
    __syncthreads();
    for (int off = 64; off > 0; off >>= 1) {
        if (tid < off) red[tid] += red[tid + off];
        __syncthreads();
    }
    if (tid == 0) {
        const float den = Cws[b] + Cws[Bn + b] + logf(red[0]);
        atomicAdd(out, num[b] - den);
    }
}

extern "C" void kernel_launch(void* const* d_in, const int* in_sizes, int n_in,
                              void* d_out, int out_size, void* d_ws, size_t ws_size,
                              hipStream_t stream)
{
    const float* em     = (const float*)d_in[0];
    const int*   tags   = (const int*)d_in[1];
    const int*   mask   = (const int*)d_in[2];
    const float* startT = (const float*)d_in[3];
    const float* endT   = (const float*)d_in[4];
    const float* trans  = (const float*)d_in[5];

    const size_t XBYTES = (size_t)Tn * Bn * Kn * 2;         // 33.5 MB
    const size_t SMALL  = 65536 + 2048 + 4096 + 524288;     // frags+num+Cws+vws
    const bool pre = (ws_size >= XBYTES + SMALL);

    char* ws = (char*)d_ws;
    u32*  X  = (u32*)ws;                                    // PRE path only
    char* base = pre ? (ws + XBYTES) : ws;
    bf16_t* frags = (bf16_t*)base;
    float*  num   = (float*)(base + 65536);
    float*  Cws   = (float*)(base + 65536 + 2048);
    float*  vws   = (float*)(base + 65536 + 2048 + 4096);
    float*  out   = (float*)d_out;

    hipLaunchKernelGGL(crf_prep, dim3(Bn + 1), dim3(128), 0, stream,
                       em, tags, mask, startT, endT, trans, frags, num, out);
    if (pre) {
        hipLaunchKernelGGL(crf_expem, dim3(4096), dim3(256), 0, stream, em, X);
        hipLaunchKernelGGL((crf_main<1>), dim3(64), dim3(256), 0, stream,
                           em, X, mask, startT, endT, frags, vws, Cws);
    } else {
        hipLaunchKernelGGL((crf_main<0>), dim3(64), dim3(256), 0, stream,
                           em, X, mask, startT, endT, frags, vws, Cws);
    }
    hipLaunchKernelGGL(crf_combine, dim3(Bn), dim3(128), 0, stream,
                       vws, Cws, num, out);
}